// Round 1
// baseline (184.556 us; speedup 1.0000x reference)
//
#include <hip/hip_runtime.h>

#define NB 4096
#define QLEN 1024
#define NL 64
#define KLEN 32
#define NS (QLEN - KLEN + 1)   // 993

__global__ __launch_bounds__(256, 4) void shapelet_kernel(
    const float* __restrict__ ts,        // [B, Q]
    const float* __restrict__ shapelets, // [L, K]
    const float* __restrict__ fc_w,      // [2, L]
    const float* __restrict__ fc_b,      // [2]
    float* __restrict__ out)             // [B, 2]
{
    __shared__ float lds_ts[QLEN + 32];      // padded so chunk reads never go OOB
    __shared__ float lds_shap[NL][KLEN + 1]; // +1 pad: conflict-free row gather
    __shared__ float lds_win[QLEN];          // win_sq, 0 for p >= NS
    __shared__ float lds_pm[4][NL];          // per-wave partial min

    const int tid  = threadIdx.x;
    const int b    = blockIdx.x;
    const int lane = tid & 63;
    const int wave = tid >> 6;

    // --- stage ts row (1024 f32, one float4 per thread, coalesced) ---
    {
        const float4* src = reinterpret_cast<const float4*>(ts + (size_t)b * QLEN);
        reinterpret_cast<float4*>(lds_ts)[tid] = src[tid];
    }
    if (tid < 32) lds_ts[QLEN + tid] = 0.0f;

    // --- stage shapelets (2048 f32) into padded LDS ---
    {
        int row = tid >> 2;            // tid/4 -> 0..63
        int col = (tid & 3) * 8;       // 0,8,16,24
        const float* src = shapelets + row * KLEN + col;
        #pragma unroll
        for (int j = 0; j < 8; ++j) lds_shap[row][col + j] = src[j];
    }
    __syncthreads();

    // --- win_sq[p] = sum_k ts[p+k]^2  (tiny: ~124 FMA/thread) ---
    for (int p = tid; p < QLEN; p += 256) {
        float acc = 0.0f;
        if (p < NS) {
            #pragma unroll
            for (int k = 0; k < KLEN; ++k) {
                float v = lds_ts[p + k];
                acc = fmaf(v, v, acc);
            }
        }
        lds_win[p] = acc;
    }
    __syncthreads();

    // --- per-lane shapelet into registers (lane l owns shapelet l) ---
    float sh[KLEN];
    #pragma unroll
    for (int k = 0; k < KLEN; ++k) sh[k] = lds_shap[lane][k];
    float ssq = 0.0f;
    #pragma unroll
    for (int k = 0; k < KLEN; ++k) ssq = fmaf(sh[k], sh[k], ssq);

    // --- main loop: wave w covers positions [256w, 256w+256), chunks of 8 ---
    const int base = wave * 256;
    float m = 3.4e38f;

    for (int c = 0; c < 256; c += 8) {
        const int p0 = base + c;
        // load ts[p0 .. p0+39] (wave-uniform addr -> LDS broadcast), float4 aligned
        float w[40];
        const float4* tsrc = reinterpret_cast<const float4*>(lds_ts + p0);
        #pragma unroll
        for (int i = 0; i < 10; ++i) {
            float4 v = tsrc[i];
            w[4 * i + 0] = v.x; w[4 * i + 1] = v.y;
            w[4 * i + 2] = v.z; w[4 * i + 3] = v.w;
        }
        #pragma unroll
        for (int j = 0; j < 8; ++j) {
            float cr = 0.0f;
            #pragma unroll
            for (int k = 0; k < KLEN; ++k) cr = fmaf(w[j + k], sh[k], cr);
            float g = fmaf(-2.0f, cr, lds_win[p0 + j]);
            if (p0 + j < NS) m = fminf(m, g);
        }
    }

    // --- cross-wave min reduce ---
    lds_pm[wave][lane] = m;
    __syncthreads();

    if (wave == 0) {
        float mm = fminf(fminf(lds_pm[0][lane], lds_pm[1][lane]),
                         fminf(lds_pm[2][lane], lds_pm[3][lane]));
        float f = (mm + ssq) * (1.0f / (float)KLEN);   // feat[b, lane]

        // fc: out[b,c] = sum_l feat[l] * fc_w[c,l] + fc_b[c]
        float p0v = f * fc_w[lane];
        float p1v = f * fc_w[NL + lane];
        #pragma unroll
        for (int off = 32; off >= 1; off >>= 1) {
            p0v += __shfl_xor(p0v, off, 64);
            p1v += __shfl_xor(p1v, off, 64);
        }
        if (lane == 0) {
            out[(size_t)b * 2 + 0] = p0v + fc_b[0];
            out[(size_t)b * 2 + 1] = p1v + fc_b[1];
        }
    }
}

extern "C" void kernel_launch(void* const* d_in, const int* in_sizes, int n_in,
                              void* d_out, int out_size, void* d_ws, size_t ws_size,
                              hipStream_t stream) {
    const float* ts        = (const float*)d_in[0];
    const float* shapelets = (const float*)d_in[1];
    const float* fc_w      = (const float*)d_in[2];
    const float* fc_b      = (const float*)d_in[3];
    float* out = (float*)d_out;

    shapelet_kernel<<<NB, 256, 0, stream>>>(ts, shapelets, fc_w, fc_b, out);
}

// Round 2
// 59.354 us; speedup vs baseline: 3.1094x; 3.1094x over previous
//
#include <hip/hip_runtime.h>
#include <stdint.h>

#define NB 4096
#define QLEN 1024
#define NL 64
#define KLEN 32
#define NS (QLEN - KLEN + 1)   // 993
#define NTILE 63               // ceil(NS / 16)
#define TSP (QLEN + 32)        // padded ts length (1056)

typedef __attribute__((ext_vector_type(8))) short short8;
typedef __attribute__((ext_vector_type(4))) float f32x4;

__global__ __launch_bounds__(256, 4) void shapelet_mfma_kernel(
    const float* __restrict__ ts,        // [B, Q]
    const float* __restrict__ shapelets, // [L, K]
    const float* __restrict__ fc_w,      // [2, L]
    const float* __restrict__ fc_b,      // [2]
    float* __restrict__ out)             // [B, 2]
{
    __shared__ __align__(16) float    lds_tsf[TSP];   // fp32 ts row (for win_sq)
    __shared__ __align__(16) uint32_t lds_pack[TSP];  // bf16_hi<<16 | bf16_lo
    __shared__ __align__(16) float    lds_win[QLEN];  // win_sq, 1e30 for s>=NS
    __shared__ float    lds_ssq[NL];
    __shared__ float    lds_pm[4][NL];

    const int tid  = threadIdx.x;
    const int b    = blockIdx.x;
    const int lane = tid & 63;
    const int wave = tid >> 6;
    const int col  = lane & 15;   // MFMA col / A-row lane group
    const int kg   = lane >> 4;   // k-group (0..3)

    // --- stage ts row: fp32 copy + hi/lo bf16 pack (1 float4 per thread) ---
    {
        float4 v = reinterpret_cast<const float4*>(ts + (size_t)b * QLEN)[tid];
        float xs[4] = {v.x, v.y, v.z, v.w};
        uint32_t pk[4];
        #pragma unroll
        for (int j = 0; j < 4; ++j) {
            uint32_t u  = __builtin_bit_cast(uint32_t, xs[j]);
            uint32_t hu = u & 0xFFFF0000u;
            float lo = xs[j] - __builtin_bit_cast(float, hu);
            pk[j] = hu | (__builtin_bit_cast(uint32_t, lo) >> 16);
        }
        reinterpret_cast<float4*>(lds_tsf)[tid] = v;
        uint4 pv = {pk[0], pk[1], pk[2], pk[3]};
        reinterpret_cast<uint4*>(lds_pack)[tid] = pv;
    }
    if (tid < 32) { lds_tsf[QLEN + tid] = 0.0f; lds_pack[QLEN + tid] = 0u; }

    // --- B fragments (all 4 l-tiles, hi+lo) into registers, from global ---
    short8 Bhi[4], Blo[4];
    #pragma unroll
    for (int lt = 0; lt < 4; ++lt) {
        const float* sp = shapelets + (lt * 16 + col) * KLEN + kg * 8;
        #pragma unroll
        for (int e = 0; e < 8; ++e) {
            float x = sp[e];
            uint32_t u  = __builtin_bit_cast(uint32_t, x);
            uint32_t hu = u & 0xFFFF0000u;
            float lo = x - __builtin_bit_cast(float, hu);
            Bhi[lt][e] = (short)(u >> 16);
            Blo[lt][e] = (short)(__builtin_bit_cast(uint32_t, lo) >> 16);
        }
    }

    // --- per-shapelet sum of squares ---
    if (tid < NL) {
        const float* sp = shapelets + tid * KLEN;
        float s = 0.0f;
        #pragma unroll
        for (int k = 0; k < KLEN; ++k) s = fmaf(sp[k], sp[k], s);
        lds_ssq[tid] = s;
    }
    __syncthreads();

    // --- win_sq[p]; 1e30 masks positions >= NS ---
    for (int p = tid; p < QLEN; p += 256) {
        float acc;
        if (p < NS) {
            acc = 0.0f;
            #pragma unroll
            for (int k = 0; k < KLEN; ++k) {
                float v = lds_tsf[p + k];
                acc = fmaf(v, v, acc);
            }
        } else {
            acc = 1.0e30f;
        }
        lds_win[p] = acc;
    }
    __syncthreads();

    // --- main loop: wave w handles s-tiles w, w+4, ...; all 4 l-tiles ---
    float rmax[4][4];
    #pragma unroll
    for (int lt = 0; lt < 4; ++lt)
        #pragma unroll
        for (int e = 0; e < 4; ++e) rmax[lt][e] = -3.0e38f;

    const int aoff = col + kg * 8;   // A: row=col(lane&15), k=kg*8+e
    for (int st = wave; st < NTILE; st += 4) {
        const int s0 = st * 16;

        uint32_t p[8];
        #pragma unroll
        for (int i = 0; i < 8; ++i) p[i] = lds_pack[s0 + aoff + i];

        union { uint32_t u[4]; short8 s; } Ahi, Alo;
        #pragma unroll
        for (int j = 0; j < 4; ++j) {
            // word j = [half(x_{2j+1}) : half(x_{2j})]
            Ahi.u[j] = __builtin_amdgcn_perm(p[2*j+1], p[2*j], 0x07060302u);
            Alo.u[j] = __builtin_amdgcn_perm(p[2*j+1], p[2*j], 0x05040100u);
        }

        // C init = -0.5 * win[s];  rows i = kg*4 + e  (16B-aligned b128 read)
        const float4 w4 = *reinterpret_cast<const float4*>(&lds_win[s0 + kg * 4]);
        f32x4 init;
        init[0] = -0.5f * w4.x; init[1] = -0.5f * w4.y;
        init[2] = -0.5f * w4.z; init[3] = -0.5f * w4.w;

        #pragma unroll
        for (int lt = 0; lt < 4; ++lt) {
            f32x4 acc = init;
            acc = __builtin_amdgcn_mfma_f32_16x16x32_bf16(Ahi.s, Bhi[lt], acc, 0, 0, 0);
            acc = __builtin_amdgcn_mfma_f32_16x16x32_bf16(Alo.s, Bhi[lt], acc, 0, 0, 0);
            acc = __builtin_amdgcn_mfma_f32_16x16x32_bf16(Ahi.s, Blo[lt], acc, 0, 0, 0);
            #pragma unroll
            for (int e = 0; e < 4; ++e) rmax[lt][e] = fmaxf(rmax[lt][e], acc[e]);
        }
    }

    // --- reduce: within-lane, cross-lane (same col), cross-wave via LDS ---
    #pragma unroll
    for (int lt = 0; lt < 4; ++lt) {
        float v = fmaxf(fmaxf(rmax[lt][0], rmax[lt][1]),
                        fmaxf(rmax[lt][2], rmax[lt][3]));
        v = fmaxf(v, __shfl_xor(v, 16, 64));
        v = fmaxf(v, __shfl_xor(v, 32, 64));
        if (kg == 0) lds_pm[wave][lt * 16 + col] = v;
    }
    __syncthreads();

    if (wave == 0) {
        float m = fmaxf(fmaxf(lds_pm[0][lane], lds_pm[1][lane]),
                        fmaxf(lds_pm[2][lane], lds_pm[3][lane]));
        // feat = (ssq - 2*max(cross - win/2)) / K  ==  min dist
        float f = (lds_ssq[lane] - 2.0f * m) * (1.0f / (float)KLEN);

        float p0v = f * fc_w[lane];
        float p1v = f * fc_w[NL + lane];
        #pragma unroll
        for (int off = 32; off >= 1; off >>= 1) {
            p0v += __shfl_xor(p0v, off, 64);
            p1v += __shfl_xor(p1v, off, 64);
        }
        if (lane == 0) {
            out[(size_t)b * 2 + 0] = p0v + fc_b[0];
            out[(size_t)b * 2 + 1] = p1v + fc_b[1];
        }
    }
}

extern "C" void kernel_launch(void* const* d_in, const int* in_sizes, int n_in,
                              void* d_out, int out_size, void* d_ws, size_t ws_size,
                              hipStream_t stream) {
    const float* ts        = (const float*)d_in[0];
    const float* shapelets = (const float*)d_in[1];
    const float* fc_w      = (const float*)d_in[2];
    const float* fc_b      = (const float*)d_in[3];
    float* out = (float*)d_out;

    shapelet_mfma_kernel<<<NB, 256, 0, stream>>>(ts, shapelets, fc_w, fc_b, out);
}

// Round 3
// 34.574 us; speedup vs baseline: 5.3379x; 1.7167x over previous
//
#include <hip/hip_runtime.h>
#include <stdint.h>

#define NB 4096
#define QLEN 1024
#define NL 64
#define KLEN 32
#define NS (QLEN - KLEN + 1)   // 993
#define TSP 1060               // padded ts length

typedef __attribute__((ext_vector_type(8))) short short8;
typedef __attribute__((ext_vector_type(4))) float f32x4;

union frag { uint32_t u[4]; short8 s; };

static __device__ __forceinline__ uint32_t rnbf16(float x) {
    uint32_t u = __builtin_bit_cast(uint32_t, x);
    return (u + 0x7FFFu + ((u >> 16) & 1u)) >> 16;   // round-to-nearest-even bf16
}

__global__ __launch_bounds__(256, 4) void shapelet_mfma2(
    const float* __restrict__ ts,        // [B, Q]
    const float* __restrict__ shapelets, // [L, K]
    const float* __restrict__ fc_w,      // [2, L]
    const float* __restrict__ fc_b,      // [2]
    float* __restrict__ out)             // [B, 2]
{
    __shared__ __align__(16) float    lds_tsf[TSP];    // fp32 ts row + zero pad
    __shared__ __align__(16) float    lds_nwin[QLEN];  // -0.5*win_sq; -1e30 for s>=NS
    __shared__ __align__(16) uint32_t lds_pkE[528];    // bf16(x[2i]) | bf16(x[2i+1])<<16
    __shared__ __align__(16) uint32_t lds_pkO[528];    // bf16(x[2i+1]) | bf16(x[2i+2])<<16
    __shared__ float lds_ssq[NL];
    __shared__ float lds_pm[4][NL];

    const int tid  = threadIdx.x;
    const int b    = blockIdx.x;
    const int lane = tid & 63;
    const int wave = tid >> 6;
    const int col  = lane & 15;
    const int kg   = lane >> 4;

    // --- stage ts row (coalesced float4) + zero pad ---
    {
        float4 v = reinterpret_cast<const float4*>(ts + (size_t)b * QLEN)[tid];
        reinterpret_cast<float4*>(lds_tsf)[tid] = v;
    }
    if (tid < TSP - QLEN) lds_tsf[QLEN + tid] = 0.0f;

    // --- B fragments: exact hi/lo truncation split, built via v_perm (global reads) ---
    frag Bhi[4], Blo[4];
    #pragma unroll
    for (int lt = 0; lt < 4; ++lt) {
        const float* sp = shapelets + (lt * 16 + col) * KLEN + kg * 8;
        float4 f0 = *reinterpret_cast<const float4*>(sp);
        float4 f1 = *reinterpret_cast<const float4*>(sp + 4);
        float xf[8] = {f0.x, f0.y, f0.z, f0.w, f1.x, f1.y, f1.z, f1.w};
        uint32_t uh[8], ul[8];
        #pragma unroll
        for (int e = 0; e < 8; ++e) {
            uh[e] = __builtin_bit_cast(uint32_t, xf[e]);
            float lo = xf[e] - __builtin_bit_cast(float, uh[e] & 0xFFFF0000u);
            ul[e] = __builtin_bit_cast(uint32_t, lo);
        }
        #pragma unroll
        for (int j = 0; j < 4; ++j) {
            Bhi[lt].u[j] = __builtin_amdgcn_perm(uh[2*j+1], uh[2*j], 0x07060302u);
            Blo[lt].u[j] = __builtin_amdgcn_perm(ul[2*j+1], ul[2*j], 0x07060302u);
        }
    }

    // --- per-shapelet sum of squares (global reads, cached) ---
    if (tid < NL) {
        const float* sp = shapelets + tid * KLEN;
        float s = 0.0f;
        #pragma unroll
        for (int k = 0; k < KLEN; ++k) s = fmaf(sp[k], sp[k], s);
        lds_ssq[tid] = s;
    }
    __syncthreads();

    // --- pass 2: win_sq (sliding) + RN-bf16 phase-packed arrays ---
    {
        float x[36];
        const float4* p4 = reinterpret_cast<const float4*>(lds_tsf + 4 * tid);
        #pragma unroll
        for (int q = 0; q < 9; ++q) {
            float4 t = p4[q];
            x[4*q+0] = t.x; x[4*q+1] = t.y; x[4*q+2] = t.z; x[4*q+3] = t.w;
        }
        float w0 = 0.0f;
        #pragma unroll
        for (int k = 0; k < KLEN; ++k) w0 = fmaf(x[k], x[k], w0);
        float w1 = fmaf(x[32], x[32], fmaf(-x[0], x[0], w0));
        float w2 = fmaf(x[33], x[33], fmaf(-x[1], x[1], w1));
        float w3 = fmaf(x[34], x[34], fmaf(-x[2], x[2], w2));
        const int p0 = 4 * tid;
        float4 wv;
        wv.x = (p0 + 0 < NS) ? -0.5f * w0 : -1.0e30f;
        wv.y = (p0 + 1 < NS) ? -0.5f * w1 : -1.0e30f;
        wv.z = (p0 + 2 < NS) ? -0.5f * w2 : -1.0e30f;
        wv.w = (p0 + 3 < NS) ? -0.5f * w3 : -1.0e30f;
        reinterpret_cast<float4*>(lds_nwin)[tid] = wv;

        uint32_t r0 = rnbf16(x[0]), r1 = rnbf16(x[1]), r2 = rnbf16(x[2]),
                 r3 = rnbf16(x[3]), r4 = rnbf16(x[4]);
        uint2 pe = { r0 | (r1 << 16), r2 | (r3 << 16) };
        uint2 po = { r1 | (r2 << 16), r3 | (r4 << 16) };
        reinterpret_cast<uint2*>(lds_pkE)[tid] = pe;
        reinterpret_cast<uint2*>(lds_pkO)[tid] = po;
    }
    if (tid < 16) { lds_pkE[512 + tid] = 0u; lds_pkO[512 + tid] = 0u; }
    __syncthreads();

    // --- main loop: 8 iterations, 2 s-tiles each (pair q = wave + 4i, s0 = 32q) ---
    float rmax[4][4];
    #pragma unroll
    for (int lt = 0; lt < 4; ++lt)
        #pragma unroll
        for (int e = 0; e < 4; ++e) rmax[lt][e] = -3.0e38f;

    const int par = col & 1;
    const uint32_t* apk = par ? lds_pkO : lds_pkE;
    const int abase = ((col - par) >> 1) + kg * 4;

    #pragma unroll 2
    for (int i = 0; i < 8; ++i) {
        const int s0 = 32 * wave + 128 * i;
        const uint32_t* ap = apk + (s0 >> 1) + abase;
        frag Aa, Ab;
        #pragma unroll
        for (int j = 0; j < 4; ++j) Aa.u[j] = ap[j];
        #pragma unroll
        for (int j = 0; j < 4; ++j) Ab.u[j] = ap[8 + j];
        const f32x4 ia = *reinterpret_cast<const f32x4*>(lds_nwin + s0 + kg * 4);
        const f32x4 ib = *reinterpret_cast<const f32x4*>(lds_nwin + s0 + 16 + kg * 4);

        #pragma unroll
        for (int lt = 0; lt < 4; ++lt) {
            f32x4 aa = __builtin_amdgcn_mfma_f32_16x16x32_bf16(Aa.s, Bhi[lt].s, ia, 0, 0, 0);
            aa       = __builtin_amdgcn_mfma_f32_16x16x32_bf16(Aa.s, Blo[lt].s, aa, 0, 0, 0);
            f32x4 ab = __builtin_amdgcn_mfma_f32_16x16x32_bf16(Ab.s, Bhi[lt].s, ib, 0, 0, 0);
            ab       = __builtin_amdgcn_mfma_f32_16x16x32_bf16(Ab.s, Blo[lt].s, ab, 0, 0, 0);
            #pragma unroll
            for (int e = 0; e < 4; ++e)
                rmax[lt][e] = fmaxf(fmaxf(aa[e], ab[e]), rmax[lt][e]);  // -> v_max3_f32
        }
    }

    // --- reduce: within-lane, cross-kg (same col), cross-wave ---
    #pragma unroll
    for (int lt = 0; lt < 4; ++lt) {
        float v = fmaxf(fmaxf(rmax[lt][0], rmax[lt][1]),
                        fmaxf(rmax[lt][2], rmax[lt][3]));
        v = fmaxf(v, __shfl_xor(v, 16, 64));
        v = fmaxf(v, __shfl_xor(v, 32, 64));
        if (kg == 0) lds_pm[wave][lt * 16 + col] = v;
    }
    __syncthreads();

    if (wave == 0) {
        float m = fmaxf(fmaxf(lds_pm[0][lane], lds_pm[1][lane]),
                        fmaxf(lds_pm[2][lane], lds_pm[3][lane]));
        float f = (lds_ssq[lane] - 2.0f * m) * (1.0f / (float)KLEN);  // min dist

        float p0v = f * fc_w[lane];
        float p1v = f * fc_w[NL + lane];
        #pragma unroll
        for (int off = 32; off >= 1; off >>= 1) {
            p0v += __shfl_xor(p0v, off, 64);
            p1v += __shfl_xor(p1v, off, 64);
        }
        if (lane == 0) {
            out[(size_t)b * 2 + 0] = p0v + fc_b[0];
            out[(size_t)b * 2 + 1] = p1v + fc_b[1];
        }
    }
}

extern "C" void kernel_launch(void* const* d_in, const int* in_sizes, int n_in,
                              void* d_out, int out_size, void* d_ws, size_t ws_size,
                              hipStream_t stream) {
    const float* ts        = (const float*)d_in[0];
    const float* shapelets = (const float*)d_in[1];
    const float* fc_w      = (const float*)d_in[2];
    const float* fc_b      = (const float*)d_in[3];
    float* out = (float*)d_out;

    shapelet_mfma2<<<NB, 256, 0, stream>>>(ts, shapelets, fc_w, fc_b, out);
}

// Round 5
// 28.526 us; speedup vs baseline: 6.4698x; 1.2120x over previous
//
#include <hip/hip_runtime.h>
#include <stdint.h>

#define NB 4096
#define QLEN 1024
#define NL 64
#define KLEN 32
#define NS (QLEN - KLEN + 1)   // 993
#define TSP 1060               // padded ts length

typedef __attribute__((ext_vector_type(8))) _Float16 half8;
typedef __attribute__((ext_vector_type(4))) float f32x4;

union fragh { uint32_t u[4]; half8 v; };

static __device__ __forceinline__ uint32_t pkh(float a, float b) {
    return __builtin_bit_cast(uint32_t, __builtin_amdgcn_cvt_pkrtz(a, b)); // v_cvt_pkrtz_f16_f32
}

__global__ __launch_bounds__(256, 6) void shapelet_mfma_f16(
    const float* __restrict__ ts,        // [B, Q]
    const float* __restrict__ shapelets, // [L, K]
    const float* __restrict__ fc_w,      // [2, L]
    const float* __restrict__ fc_b,      // [2]
    float* __restrict__ out)             // [B, 2]
{
    __shared__ __align__(16) float    lds_tsf[TSP];    // fp32 ts row + zero pad
    __shared__ __align__(16) float    lds_nwin[QLEN];  // -0.5*win_sq; -1e30 for s>=NS
    __shared__ __align__(16) uint32_t lds_pkE[528];    // f16(x[2i]) | f16(x[2i+1])<<16
    __shared__ __align__(16) uint32_t lds_pkO[528];    // f16(x[2i+1]) | f16(x[2i+2])<<16
    __shared__ float lds_ssq[NL];
    __shared__ float lds_pm[4][NL];

    const int tid  = threadIdx.x;
    const int b    = blockIdx.x;
    const int lane = tid & 63;
    const int wave = tid >> 6;
    const int col  = lane & 15;
    const int kg   = lane >> 4;

    // --- stage ts row (coalesced float4) + zero pad ---
    {
        float4 v = reinterpret_cast<const float4*>(ts + (size_t)b * QLEN)[tid];
        reinterpret_cast<float4*>(lds_tsf)[tid] = v;
    }
    if (tid < TSP - QLEN) lds_tsf[QLEN + tid] = 0.0f;

    // --- B fragments: fp16 RTZ, all 4 l-tiles (16 VGPR) ---
    fragh Bh[4];
    #pragma unroll
    for (int lt = 0; lt < 4; ++lt) {
        const float* sp = shapelets + (lt * 16 + col) * KLEN + kg * 8;
        float4 f0 = *reinterpret_cast<const float4*>(sp);
        float4 f1 = *reinterpret_cast<const float4*>(sp + 4);
        Bh[lt].u[0] = pkh(f0.x, f0.y);
        Bh[lt].u[1] = pkh(f0.z, f0.w);
        Bh[lt].u[2] = pkh(f1.x, f1.y);
        Bh[lt].u[3] = pkh(f1.z, f1.w);
    }

    // --- per-shapelet sum of squares (fp32, global reads, L2-cached) ---
    if (tid < NL) {
        const float* sp = shapelets + tid * KLEN;
        float s = 0.0f;
        #pragma unroll
        for (int k = 0; k < KLEN; ++k) s = fmaf(sp[k], sp[k], s);
        lds_ssq[tid] = s;
    }
    __syncthreads();

    // --- pass 2: win_sq (sliding) + fp16 phase-packed arrays ---
    {
        float x[36];
        const float4* p4 = reinterpret_cast<const float4*>(lds_tsf + 4 * tid);
        #pragma unroll
        for (int q = 0; q < 9; ++q) {
            float4 t = p4[q];
            x[4*q+0] = t.x; x[4*q+1] = t.y; x[4*q+2] = t.z; x[4*q+3] = t.w;
        }
        float w0 = 0.0f;
        #pragma unroll
        for (int k = 0; k < KLEN; ++k) w0 = fmaf(x[k], x[k], w0);
        float w1 = fmaf(x[32], x[32], fmaf(-x[0], x[0], w0));
        float w2 = fmaf(x[33], x[33], fmaf(-x[1], x[1], w1));
        float w3 = fmaf(x[34], x[34], fmaf(-x[2], x[2], w2));
        const int p0 = 4 * tid;
        float4 wv;
        wv.x = (p0 + 0 < NS) ? -0.5f * w0 : -1.0e30f;
        wv.y = (p0 + 1 < NS) ? -0.5f * w1 : -1.0e30f;
        wv.z = (p0 + 2 < NS) ? -0.5f * w2 : -1.0e30f;
        wv.w = (p0 + 3 < NS) ? -0.5f * w3 : -1.0e30f;
        reinterpret_cast<float4*>(lds_nwin)[tid] = wv;

        uint2 pe = { pkh(x[0], x[1]), pkh(x[2], x[3]) };
        uint2 po = { pkh(x[1], x[2]), pkh(x[3], x[4]) };
        reinterpret_cast<uint2*>(lds_pkE)[tid] = pe;
        reinterpret_cast<uint2*>(lds_pkO)[tid] = po;
    }
    if (tid < 16) { lds_pkE[512 + tid] = 0u; lds_pkO[512 + tid] = 0u; }
    __syncthreads();

    // --- main loop: 8 iterations, 2 s-tiles each, 1 fp16 MFMA per (tile, lt) ---
    float rmax[4][4];
    #pragma unroll
    for (int lt = 0; lt < 4; ++lt)
        #pragma unroll
        for (int e = 0; e < 4; ++e) rmax[lt][e] = -3.0e38f;

    const int par = col & 1;
    const uint32_t* apk = par ? lds_pkO : lds_pkE;
    const int abase = ((col - par) >> 1) + kg * 4;

    #pragma unroll 2
    for (int i = 0; i < 8; ++i) {
        const int s0 = 32 * wave + 128 * i;
        const uint32_t* ap = apk + (s0 >> 1) + abase;
        fragh Aa, Ab;
        #pragma unroll
        for (int j = 0; j < 4; ++j) Aa.u[j] = ap[j];
        #pragma unroll
        for (int j = 0; j < 4; ++j) Ab.u[j] = ap[8 + j];
        const f32x4 ia = *reinterpret_cast<const f32x4*>(lds_nwin + s0 + kg * 4);
        const f32x4 ib = *reinterpret_cast<const f32x4*>(lds_nwin + s0 + 16 + kg * 4);

        #pragma unroll
        for (int lt = 0; lt < 4; ++lt) {
            f32x4 aa = __builtin_amdgcn_mfma_f32_16x16x32_f16(Aa.v, Bh[lt].v, ia, 0, 0, 0);
            f32x4 ab = __builtin_amdgcn_mfma_f32_16x16x32_f16(Ab.v, Bh[lt].v, ib, 0, 0, 0);
            #pragma unroll
            for (int e = 0; e < 4; ++e)
                rmax[lt][e] = fmaxf(fmaxf(aa[e], ab[e]), rmax[lt][e]);  // -> v_max3_f32
        }
    }

    // --- reduce: within-lane, cross-kg (same col), cross-wave ---
    #pragma unroll
    for (int lt = 0; lt < 4; ++lt) {
        float v = fmaxf(fmaxf(rmax[lt][0], rmax[lt][1]),
                        fmaxf(rmax[lt][2], rmax[lt][3]));
        v = fmaxf(v, __shfl_xor(v, 16, 64));
        v = fmaxf(v, __shfl_xor(v, 32, 64));
        if (kg == 0) lds_pm[wave][lt * 16 + col] = v;
    }
    __syncthreads();

    if (wave == 0) {
        float m = fmaxf(fmaxf(lds_pm[0][lane], lds_pm[1][lane]),
                        fmaxf(lds_pm[2][lane], lds_pm[3][lane]));
        float f = (lds_ssq[lane] - 2.0f * m) * (1.0f / (float)KLEN);  // min dist

        float p0v = f * fc_w[lane];
        float p1v = f * fc_w[NL + lane];
        #pragma unroll
        for (int off = 32; off >= 1; off >>= 1) {
            p0v += __shfl_xor(p0v, off, 64);
            p1v += __shfl_xor(p1v, off, 64);
        }
        if (lane == 0) {
            out[(size_t)b * 2 + 0] = p0v + fc_b[0];
            out[(size_t)b * 2 + 1] = p1v + fc_b[1];
        }
    }
}

extern "C" void kernel_launch(void* const* d_in, const int* in_sizes, int n_in,
                              void* d_out, int out_size, void* d_ws, size_t ws_size,
                              hipStream_t stream) {
    const float* ts        = (const float*)d_in[0];
    const float* shapelets = (const float*)d_in[1];
    const float* fc_w      = (const float*)d_in[2];
    const float* fc_b      = (const float*)d_in[3];
    float* out = (float*)d_out;

    shapelet_mfma_f16<<<NB, 256, 0, stream>>>(ts, shapelets, fc_w, fc_b, out);
}